// Round 4
// baseline (108.778 us; speedup 1.0000x reference)
//
#include <hip/hip_runtime.h>

// Fast discrete Radon transform (exact, wrap-around shears), radix-16:
//   case A (m<512):   R_m[t]  = sum_y img[(t - m*y) & 511, y]
//   case B (m>=512):  R'_a[t] = sum_x img[x, (t - 2a*x) & 511], a = m-512
// out = R * (1/sqrt(512)), imag exactly 0.
//
// D_q[c][w][x] = sum_{u<q} A'[u*h+w][(x - c*u*h) & 511],  h = 512/q
// D_{16q}[C][w][x] = sum_{b<16} D_q[C mod q][w + b*H][(x - C*b*H) & 511]
// Stages: 1 ->(init, radix-2) 2 ->(radix-16) 32 ->(radix-16, fused output) 512.
// Case B keeps only even classes (256 rows).
//
// Pass-2 rotation trick: stage-32 row (c,bb) is consumed by exactly one
// pass-2 block, so stage it into LDS rotated by c*bb; all compute reads then
// have shifts that are multiples of 32 -> aligned wrap-free ds_read_b128.

#define NN 512
#define MU 768
#define MASK 511
#define SCALE 0.04419417382415922f  // 1/sqrt(512)

// ---- init: blocks 0..31 A (transpose + radix-2), 32..39 B (radix-2) ------
__global__ __launch_bounds__(256) void k_init(const float* __restrict__ img,
                                              float* __restrict__ A0,
                                              float* __restrict__ B0) {
  const int bx = blockIdx.x, b = blockIdx.y;
  const float* src = img + (size_t)b * NN * NN;
  if (bx < 32) {
    __shared__ float T1[64][65], T2[64][65], T3[64][65];
    const int xt = bx & 7, wt = bx >> 3;
    const int x0 = xt * 64, w0 = wt * 64, x3 = ((xt + 4) & 7) * 64;
    for (int idx = threadIdx.x; idx < 4096; idx += 256) {
      int rr = idx >> 6, cc = idx & 63;
      T1[rr][cc] = src[(x0 + rr) * NN + w0 + cc];
      T2[rr][cc] = src[(x0 + rr) * NN + w0 + 256 + cc];
      T3[rr][cc] = src[(x3 + rr) * NN + w0 + 256 + cc];
    }
    __syncthreads();
    float* dst = A0 + (size_t)b * (512 * NN);
    for (int idx = threadIdx.x; idx < 4096; idx += 256) {
      int wl = idx >> 6, xl = idx & 63;
      float t1 = T1[xl][wl];
      dst[(size_t)(w0 + wl) * NN + x0 + xl]       = t1 + T2[xl][wl];
      dst[(size_t)(256 + w0 + wl) * NN + x0 + xl] = t1 + T3[xl][wl];
    }
  } else {
    const int w0 = (bx - 32) * 32;  // 32 rows per block
    const float4* s4 = (const float4*)src;
    float4* d4 = (float4*)(B0 + (size_t)b * (256 * NN));
    for (int it = 0; it < 16; ++it) {
      int flat = it * 256 + threadIdx.x;  // 4096 float4 = 32 rows x 128
      int row = w0 + (flat >> 7), col = flat & 127;
      float4 u = s4[row * 128 + col], v = s4[(row + 256) * 128 + col];
      u.x += v.x; u.y += v.y; u.z += v.z; u.w += v.w;
      d4[row * 128 + col] = u;
    }
  }
}

// ---- pass 1: stage 2 -> 32 (H=16, shifts %16==0 -> float4 LDS reads) -----
__global__ __launch_bounds__(512, 6) void k_pass1(const float* __restrict__ A0,
                                                  const float* __restrict__ B0,
                                                  float* __restrict__ A1,
                                                  float* __restrict__ B1) {
  __shared__ float L[16 * 512];
  const int bx = blockIdx.x, b = blockIdx.y;
  const int t = threadIdx.x;
  const bool isB = bx >= 32;
  const int c = isB ? 0 : (bx >> 4);
  const int w = isB ? (bx - 32) : (bx & 15);
  const float* in = isB ? (B0 + (size_t)b * 256 * NN) : (A0 + (size_t)b * 512 * NN);
  {
    const float4* s4 = (const float4*)in;
    float4* l4 = (float4*)L;
    const int pbase = c * 256 + w;  // parent row bb: pbase + 16*bb
    for (int it = 0; it < 4; ++it) {
      int flat = it * 512 + t;      // 2048 float4
      int lrow = flat >> 7, col = flat & 127;
      l4[lrow * 128 + col] = s4[(pbase + 16 * lrow) * 128 + col];
    }
  }
  __syncthreads();
  const int g = t >> 7;            // 0..3
  const int x4 = (t & 127) * 4;
  float* outA = A1 + (size_t)b * 512 * NN;
  float* outB = B1 + (size_t)b * 256 * NN;
  for (int jj = 0; jj < 4; ++jj) {
    const int j = jj * 4 + g;
    const int C = isB ? (2 * j) : (c + 2 * j);
    float4 acc = {0.f, 0.f, 0.f, 0.f};
#pragma unroll
    for (int bb = 0; bb < 16; ++bb) {
      int base = (x4 - C * bb * 16) & MASK;  // %4==0: no wrap split
      float4 v = *(const float4*)&L[bb * 512 + base];
      acc.x += v.x; acc.y += v.y; acc.z += v.z; acc.w += v.w;
    }
    const int orow = isB ? (j * 16 + w) : (C * 16 + w);
    float* op = isB ? outB : outA;
    *(float4*)&op[(size_t)orow * NN + x4] = acc;
  }
}

// ---- pass 2: stage 32 -> 512, rotated staging + b128 reads, fused out ----
__global__ __launch_bounds__(512, 6) void k_pass2(const float* __restrict__ A1,
                                                  const float* __restrict__ B1,
                                                  float2* __restrict__ out) {
  __shared__ float L[16 * 512];
  const int bx = blockIdx.x, b = blockIdx.y;
  const int t = threadIdx.x;
  const bool isB = bx >= 32;
  const int c = isB ? 2 * (bx - 32) : bx;  // stage-32 class
  const float* in = isB ? (B1 + (size_t)b * 256 * NN + (size_t)(bx - 32) * 16 * NN)
                        : (A1 + (size_t)b * 512 * NN + (size_t)c * 16 * NN);
  // stage 16 rows, row bb rotated by c*bb: L[bb][(x + c*bb)&511] = in[bb][x]
  // scalar b32: consecutive lanes -> consecutive banks (conflict-free)
#pragma unroll
  for (int bb = 0; bb < 16; ++bb) {
    float v = in[bb * 512 + t];
    L[bb * 512 + ((t + c * bb) & MASK)] = v;
  }
  __syncthreads();
  const int g = t >> 7;             // j-group: j = 4*g + jj
  const int xq = (t & 127) << 2;
  float4 acc[4];
#pragma unroll
  for (int jj = 0; jj < 4; ++jj) acc[jj] = {0.f, 0.f, 0.f, 0.f};
#pragma unroll
  for (int bb = 0; bb < 16; ++bb) {
    const float* row = L + bb * 512;
    int base = (xq - 128 * g * bb) & MASK;   // shift 32*j*bb, j=4g -> multiple of 32
    const int step = (32 * bb) & MASK;
#pragma unroll
    for (int jj = 0; jj < 4; ++jj) {
      float4 v = *(const float4*)&row[base];  // base%4==0, <=508: aligned, no wrap
      acc[jj].x += v.x; acc[jj].y += v.y; acc[jj].z += v.z; acc[jj].w += v.w;
      base = (base - step) & MASK;
    }
  }
#pragma unroll
  for (int jj = 0; jj < 4; ++jj) {
    const int j = 4 * g + jj;
    const int m = isB ? (512 + (bx - 32) + 16 * j) : (c + 32 * j);
    float2* op = out + ((size_t)b * MU + m) * NN + xq;
    float4 a = acc[jj];
    op[0] = {a.x * SCALE, 0.f};
    op[1] = {a.y * SCALE, 0.f};
    op[2] = {a.z * SCALE, 0.f};
    op[3] = {a.w * SCALE, 0.f};
  }
}

// ================= fallback: round-1 direct shear-sum =====================
#define TM 16
#define YT 16
#define LDS_STRIDE 516
__global__ __launch_bounds__(512) void drt_main(const float* __restrict__ img,
                                                float* __restrict__ out) {
  __shared__ float rows[YT * LDS_STRIDE];
  const int b = blockIdx.y;
  const int tile = blockIdx.x;
  const int t = threadIdx.x;
  const bool caseB = (tile >= 32);
  const int a0 = caseB ? (tile - 32) * TM : tile * TM;
  const float* __restrict__ src = img + (size_t)b * (NN * NN);
  const int slope0 = caseB ? (2 * a0) : a0;
  const int dslope = caseB ? 2 : 1;
  float acc[TM];
#pragma unroll
  for (int i = 0; i < TM; ++i) acc[i] = 0.0f;
  for (int y0 = 0; y0 < NN; y0 += YT) {
    __syncthreads();
    if (caseB) {
#pragma unroll
      for (int r = 0; r < YT; ++r) rows[r * LDS_STRIDE + t] = src[(y0 + r) * NN + t];
    } else {
#pragma unroll
      for (int rep = 0; rep < YT; ++rep) {
        int idx = rep * NN + t;
        int xx = idx >> 4, cc = idx & 15;
        rows[cc * LDS_STRIDE + xx] = src[xx * NN + y0 + cc];
      }
    }
    __syncthreads();
#pragma unroll 4
    for (int r = 0; r < YT; ++r) {
      const int v = y0 + r;
      int base = t - slope0 * v;
      const int step = dslope * v;
      const float* __restrict__ rowp = rows + r * LDS_STRIDE;
#pragma unroll
      for (int i = 0; i < TM; ++i) { acc[i] += rowp[base & MASK]; base -= step; }
    }
  }
  const int m = caseB ? (NN + a0) : a0;
  float2* outp = (float2*)out;
#pragma unroll
  for (int i = 0; i < TM; ++i) {
    float2 vv; vv.x = acc[i] * SCALE; vv.y = 0.0f;
    outp[((size_t)b * MU + (m + i)) * NN + t] = vv;
  }
}

extern "C" void kernel_launch(void* const* d_in, const int* in_sizes, int n_in,
                              void* d_out, int out_size, void* d_ws, size_t ws_size,
                              hipStream_t stream) {
  const float* img = (const float*)d_in[0];
  if (ws_size < (size_t)51 * 1024 * 1024) {
    drt_main<<<dim3(48, 16), dim3(512), 0, stream>>>(img, (float*)d_out);
    return;
  }
  float* W  = (float*)d_ws;
  float* A0 = W;                 // 16 x 512 x 512
  float* A1 = W + 4194304;       // 16 x 512 x 512
  float* B0 = W + 8388608;       // 16 x 256 x 512
  float* B1 = W + 10485760;      // 16 x 256 x 512

  k_init <<<dim3(40, 16), dim3(256), 0, stream>>>(img, A0, B0);
  k_pass1<<<dim3(48, 16), dim3(512), 0, stream>>>(A0, B0, A1, B1);
  k_pass2<<<dim3(48, 16), dim3(512), 0, stream>>>(A1, B1, (float2*)d_out);
}